// Round 5
// baseline (298.090 us; speedup 1.0000x reference)
//
#include <hip/hip_runtime.h>

// Blocks SNN forward: T=1024, TB=8, B=32, N=1024.
// One thread per (b,n) chain; 128 sequential time-blocks per thread.
// State in f64 to match the harness's float64 numpy reference on every
// heaviside decision (fp32 reassociation flips ~1e-7 margins).
//
// R5 (= R4 with compile fix): vmcnt ops per body cut 16 -> 4. gfx9 vmcnt
// retires IN ORDER and stores share the counter, so R3's 16 ops/body
// capped lookahead at 3 bodies (< HBM latency) -> latency-bound at 87us.
//   loads:  2x global_load_lds size=16 (per-lane addr -> 4 rows/instr)
//   stores: stage spikes in LDS, 2x global_store_dwordx4 per body
// PF=8 blocks, steady wait vmcnt(28), prefetch distance ~7 bodies.
// Fix vs R4: nontemporal_store needs clang ext_vector_type, not HIP float4.

constexpr int T_LEN = 1024;
constexpr int TB    = 8;
constexpr int NBLK  = T_LEN / TB;   // 128
constexpr int BATCH = 32;
constexpr int NOUT  = 1024;
constexpr int BN    = BATCH * NOUT; // 32768 chains
constexpr int PF    = 8;            // prefetch depth (blocks)
constexpr int SLOTS = 9;            // LDS ring slots (> PF)

#define WAITVM(N)  asm volatile("s_waitcnt vmcnt(" #N ")" ::: "memory")
#define WAITLGKM0  asm volatile("s_waitcnt lgkmcnt(0)" ::: "memory")

typedef const __attribute__((address_space(1))) void* gptr_t;
typedef __attribute__((address_space(3))) void*       sptr_t;
typedef float f4 __attribute__((ext_vector_type(4)));

__global__ __launch_bounds__(64, 1)
void snn_blocks_kernel(const float* __restrict__ x,
                       const float* __restrict__ beta_raw,
                       const float* __restrict__ p_raw,
                       const float* __restrict__ b_raw,
                       float* __restrict__ out)
{
    __shared__ float ldsin[SLOTS][TB][64];  // input ring: 9 x 2KB
    __shared__ float sbuf[TB][64];          // output staging: 2KB

    const int lane = threadIdx.x;
    const int wg0  = blockIdx.x * 64;       // flat chain offset of this WG
    const int gid  = wg0 + lane;            // = b*NOUT + n
    const int n    = gid & (NOUT - 1);

    // per-lane row/col split for the 16B-per-lane load/store pattern:
    // lane i handles row (i>>4) [+4 for the 2nd instr], cols (i&15)*4..+3
    const int rowoff = lane >> 4;
    const int coloff = wg0 + (lane & 15) * 4;

    // clamped properties (f64)
    double beta = (double)beta_raw[n];
    beta = beta < 0.001 ? 0.001 : (beta > 0.999 ? 0.999 : beta);
    double p = fabs((double)p_raw[n]);
    p = p > 0.999 ? 0.999 : p;
    double bb = fabs((double)b_raw[n]);
    bb = bb < 0.001 ? 0.001 : (bb > 1.0 ? 1.0 : bb);
    const double inv_p = 1.0 / p;

    double ppow[9];                 // p^0 .. p^8
    ppow[0] = 1.0;
#pragma unroll
    for (int i = 1; i <= 8; ++i) ppow[i] = ppow[i - 1] * p;

    double bbp[8];                  // bb * p^(t+1)
#pragma unroll
    for (int t = 0; t < 8; ++t) bbp[t] = bb * ppow[t + 1];

    // carry state
    double m = 0.0;                 // running membrane / int_mem
    double a = 0.0;                 // a_kernel scalar (a_k[t] = p^(t+1)*a)
    int    maskf = 0;               // any spike (z==1) in prev block
    int    decay = 0;               // count(z>1) in prev block
    double ssum  = 0.0;             // sum_t p^(t+1)*spike[t] of prev block
    int    zzero = 0xFF;            // bit t set if prev z[t]==0

    // preamble: stage blocks 0..PF-1 (2 dwordx4-LDS loads per block)
#pragma unroll
    for (int k = 0; k < PF; ++k) {
#pragma unroll
        for (int h = 0; h < 2; ++h) {
            const float* src = x + (ptrdiff_t)(k * TB + h * 4 + rowoff) * BN + coloff;
            __builtin_amdgcn_global_load_lds((gptr_t)src,
                                             (sptr_t)&ldsin[k][h * 4][0],
                                             16, 0, 0);
        }
    }

    int rs = 0;            // read slot
    int ws = PF % SLOTS;   // write slot for block blk+PF

    auto body = [&](int blk) {
        // consume block blk from ldsin[rs] (caller did the vmcnt gate)
        float cur[8];
#pragma unroll
        for (int t = 0; t < 8; ++t) cur[t] = ldsin[rs][t][lane];

        // block header from previous block's stats
        const double a_at = a * ssum + inv_p;
        double pd = 1.0;                        // p^decay, decay in [0,8]
        pd *= (decay & 1) ? p       : 1.0;
        pd *= (decay & 2) ? ppow[2] : 1.0;
        pd *= (decay & 4) ? ppow[4] : 1.0;
        pd *= (decay & 8) ? ppow[8] : 1.0;
        const double new_a = a_at * pd;

        if (maskf) { a = new_a;     m = 0.0; }  // v_init = 0
        else       { a = ppow[8] * a;        }  // keep int_mem

        int nmaskf = 0, ndecay = 0, nzzero = 0;
        double nssum = 0.0;
        int c = 0, zc = 0;
#pragma unroll
        for (int t = 0; t < 8; ++t) {
            double xv = (double)cur[t];
            if (maskf && ((zzero >> t) & 1)) xv = 0.0;  // refractory mask
            m = beta * m + xv;                           // causal decayed sum
            const double vth = 1.0 + bbp[t] * a;         // 1 + bb*p^(t+1)*a
            const int f = (m - vth > 0.0) ? 1 : 0;       // heaviside (strict >)
            c  += f;                                     // cumsum(faulty)
            zc += c;                                     // double cumsum
            nmaskf |= (zc == 1);
            ndecay += (zc > 1) ? 1 : 0;
            nssum  += (zc == 1) ? ppow[t + 1] : 0.0;
            nzzero |= (zc == 0) ? (1 << t) : 0;
            sbuf[t][lane] = (zc == 1) ? 1.0f : 0.0f;     // stage spike
        }
        maskf = nmaskf; decay = ndecay; ssum = nssum; zzero = nzzero;

        // drain staged spikes: 2 x dwordx4 per body (lane-transposed)
        WAITLGKM0;
        {
            const float* sflat = &sbuf[0][0];
            f4 v0 = *(const f4*)(sflat + lane * 4);
            f4 v1 = *(const f4*)(sflat + 256 + lane * 4);
            float* d0 = out + (ptrdiff_t)(blk * TB + rowoff) * BN + coloff;
            float* d1 = out + (ptrdiff_t)(blk * TB + 4 + rowoff) * BN + coloff;
            __builtin_nontemporal_store(v0, (f4*)d0);
            __builtin_nontemporal_store(v1, (f4*)d1);
        }

        // prefetch block blk+PF into slot ws
        const int pfb = blk + PF;
        if (pfb < NBLK) {
#pragma unroll
            for (int h = 0; h < 2; ++h) {
                const float* src = x + (ptrdiff_t)(pfb * TB + h * 4 + rowoff) * BN + coloff;
                __builtin_amdgcn_global_load_lds((gptr_t)src,
                                                 (sptr_t)&ldsin[ws][h * 4][0],
                                                 16, 0, 0);
            }
        }
        if (++rs == SLOTS) rs = 0;
        if (++ws == SLOTS) ws = 0;
    };

    // ramp: newer-op count after block j's preamble loads = 14 + 2j
    WAITVM(14); body(0);
    WAITVM(16); body(1);
    WAITVM(18); body(2);
    WAITVM(20); body(3);
    WAITVM(22); body(4);
    WAITVM(24); body(5);
    WAITVM(26); body(6);
    WAITVM(28); body(7);
    for (int blk = PF; blk < NBLK - PF; ++blk) {
        WAITVM(28);          // (PF-1) bodies x 4 ops
        body(blk);
    }
    for (int blk = NBLK - PF; blk < NBLK; ++blk) {
        WAITVM(14);          // tail lower bound (stricter than needed = safe)
        body(blk);
    }
}

extern "C" void kernel_launch(void* const* d_in, const int* in_sizes, int n_in,
                              void* d_out, int out_size, void* d_ws, size_t ws_size,
                              hipStream_t stream) {
    const float* x        = (const float*)d_in[0];
    const float* beta_raw = (const float*)d_in[1];
    const float* p_raw    = (const float*)d_in[2];
    const float* b_raw    = (const float*)d_in[3];
    float* out            = (float*)d_out;

    dim3 grid(BN / 64);   // 512 workgroups of 1 wave
    dim3 block(64);
    snn_blocks_kernel<<<grid, block, 0, stream>>>(x, beta_raw, p_raw, b_raw, out);
}

// Round 6
// 250.893 us; speedup vs baseline: 1.1881x; 1.1881x over previous
//
#include <hip/hip_runtime.h>

// Blocks SNN forward: T=1024, TB=8, B=32, N=1024.
// One thread per (b,n) chain; 128 sequential time-blocks per thread.
// State in f64 to match the harness's float64 numpy reference on every
// heaviside decision (fp32 reassociation flips ~1e-7 margins).
//
// R6: register pipeline via inline-asm global_load_dwordx4. R3/R5 showed the
// compiler inserts its own s_waitcnt vmcnt(0) before ds_reads aliasing
// global_load_lds destinations -> LDS-DMA pipelines get drained every body.
// Inline-asm loads are opaque to the waitcnt pass; consumption is gated by a
// register-tied s_waitcnt vmcnt(N) ("+v" on the frame regs). 4 vmcnt
// ops/body (2 loads + 2 dwordx4 nt stores), PF=16 frames, steady vmcnt(60).
// Lane-transpose in/out through small LDS buffers (plain ds ops, no DMA).

constexpr int T_LEN = 1024;
constexpr int TB    = 8;
constexpr int NBLK  = T_LEN / TB;   // 128
constexpr int BATCH = 32;
constexpr int NOUT  = 1024;
constexpr int BN    = BATCH * NOUT; // 32768 chains
constexpr int PF    = 16;           // prefetch depth (blocks) = frame count

typedef float f4 __attribute__((ext_vector_type(4)));

// register-tied vmcnt gate: frame regs are "+v" so their uses can't be
// scheduled above the wait, and the wait can't drop below the loads.
#define WAITVM_T(N, A, B) \
    asm volatile("s_waitcnt vmcnt(" #N ")" : "+v"(A), "+v"(B) :: "memory")

// pinned 16B load; opaque to the compiler's waitcnt-insertion pass.
#define GLOAD(DST, ADDR) \
    asm volatile("global_load_dwordx4 %0, %1, off" \
                 : "=v"(DST) : "v"(ADDR) : "memory")

__global__ __launch_bounds__(64, 1)
void snn_blocks_kernel(const float* __restrict__ x,
                       const float* __restrict__ beta_raw,
                       const float* __restrict__ p_raw,
                       const float* __restrict__ b_raw,
                       float* __restrict__ out)
{
    __shared__ float inbuf[TB][64];   // 2KB: load-transpose staging
    __shared__ float sbuf[TB][64];    // 2KB: store-transpose staging

    const int lane = threadIdx.x;
    const int wg0  = blockIdx.x * 64;       // flat chain offset of this WG
    const int gid  = wg0 + lane;            // = b*NOUT + n
    const int n    = gid & (NOUT - 1);

    // 16B-per-lane split: lane i handles row (i>>4) [+4 for 2nd op],
    // cols (i&15)*4..+3 of the 64-chain stripe.
    const int rowoff = lane >> 4;
    const int coloff = wg0 + (lane & 15) * 4;

    // clamped properties (f64)
    double beta = (double)beta_raw[n];
    beta = beta < 0.001 ? 0.001 : (beta > 0.999 ? 0.999 : beta);
    double p = fabs((double)p_raw[n]);
    p = p > 0.999 ? 0.999 : p;
    double bb = fabs((double)b_raw[n]);
    bb = bb < 0.001 ? 0.001 : (bb > 1.0 ? 1.0 : bb);
    const double inv_p = 1.0 / p;

    double ppow[9];                 // p^0 .. p^8
    ppow[0] = 1.0;
#pragma unroll
    for (int i = 1; i <= 8; ++i) ppow[i] = ppow[i - 1] * p;

    double bbp[8];                  // bb * p^(t+1)
#pragma unroll
    for (int t = 0; t < 8; ++t) bbp[t] = bb * ppow[t + 1];

    // carry state
    double m = 0.0;                 // running membrane / int_mem
    double a = 0.0;                 // a_kernel scalar (a_k[t] = p^(t+1)*a)
    int    maskf = 0;               // any spike (z==1) in prev block
    int    decay = 0;               // count(z>1) in prev block
    double ssum  = 0.0;             // sum_t p^(t+1)*spike[t] of prev block
    int    zzero = 0xFF;            // bit t set if prev z[t]==0

    f4 fr[PF][2];                   // rotating frames (constant-indexed only)

    // preamble: issue loads for blocks 0..PF-1 (2 x dwordx4 per block)
#pragma unroll
    for (int k = 0; k < PF; ++k) {
        GLOAD(fr[k][0], x + (ptrdiff_t)(k * TB + rowoff) * BN + coloff);
        GLOAD(fr[k][1], x + (ptrdiff_t)(k * TB + 4 + rowoff) * BN + coloff);
    }

    auto body = [&](int blk, f4 v0, f4 v1) {
        // transpose frame -> per-chain via LDS (plain ds ops; compiler
        // inserts correct lgkm waits; same-wave DS executes in order)
        *(f4*)&inbuf[rowoff][(lane & 15) * 4]     = v0;
        *(f4*)&inbuf[rowoff + 4][(lane & 15) * 4] = v1;
        float cur[8];
#pragma unroll
        for (int t = 0; t < 8; ++t) cur[t] = inbuf[t][lane];

        // block header from previous block's stats
        const double a_at = a * ssum + inv_p;
        double pd = 1.0;                        // p^decay, decay in [0,8]
        pd *= (decay & 1) ? p       : 1.0;
        pd *= (decay & 2) ? ppow[2] : 1.0;
        pd *= (decay & 4) ? ppow[4] : 1.0;
        pd *= (decay & 8) ? ppow[8] : 1.0;
        const double new_a = a_at * pd;

        if (maskf) { a = new_a;     m = 0.0; }  // v_init = 0
        else       { a = ppow[8] * a;        }  // keep int_mem

        int nmaskf = 0, ndecay = 0, nzzero = 0;
        double nssum = 0.0;
        int c = 0, zc = 0;
#pragma unroll
        for (int t = 0; t < 8; ++t) {
            double xv = (double)cur[t];
            if (maskf && ((zzero >> t) & 1)) xv = 0.0;  // refractory mask
            m = beta * m + xv;                           // causal decayed sum
            const double vth = 1.0 + bbp[t] * a;         // 1 + bb*p^(t+1)*a
            const int f = (m - vth > 0.0) ? 1 : 0;       // heaviside (strict >)
            c  += f;                                     // cumsum(faulty)
            zc += c;                                     // double cumsum
            nmaskf |= (zc == 1);
            ndecay += (zc > 1) ? 1 : 0;
            nssum  += (zc == 1) ? ppow[t + 1] : 0.0;
            nzzero |= (zc == 0) ? (1 << t) : 0;
            sbuf[t][lane] = (zc == 1) ? 1.0f : 0.0f;     // stage spike
        }
        maskf = nmaskf; decay = ndecay; ssum = nssum; zzero = nzzero;

        // drain staged spikes: 2 x dwordx4 nt stores (lane-transposed)
        const float* sflat = &sbuf[0][0];
        f4 s0 = *(const f4*)(sflat + lane * 4);
        f4 s1 = *(const f4*)(sflat + 256 + lane * 4);
        __builtin_nontemporal_store(
            s0, (f4*)(out + (ptrdiff_t)(blk * TB + rowoff) * BN + coloff));
        __builtin_nontemporal_store(
            s1, (f4*)(out + (ptrdiff_t)(blk * TB + 4 + rowoff) * BN + coloff));
    };

    // per body: 2 stores + 2 loads = 4 vmcnt ops. Frame for body blk was
    // loaded at body blk-16 -> 15 intervening bodies x 4 ops = vmcnt(60).
#define STEP(N, BLK, SL) do {                                              \
        WAITVM_T(N, fr[SL][0], fr[SL][1]);                                 \
        body((BLK), fr[SL][0], fr[SL][1]);                                 \
        const int pfb = (BLK) + PF;                                        \
        GLOAD(fr[SL][0], x + (ptrdiff_t)(pfb * TB + rowoff) * BN + coloff);\
        GLOAD(fr[SL][1], x + (ptrdiff_t)(pfb * TB + 4 + rowoff) * BN + coloff);\
    } while (0)

#define STEPT(N, BLK, SL) do {                                             \
        WAITVM_T(N, fr[SL][0], fr[SL][1]);                                 \
        body((BLK), fr[SL][0], fr[SL][1]);                                 \
    } while (0)

    // ramp: required wait for body j is 30+2j; vmcnt(30) is uniformly safe
    // (stricter) and only costs during startup.
#pragma unroll
    for (int j = 0; j < 16; ++j) STEP(30, j, j);

    // steady state: bodies 16..111, loads for 32..127
#pragma unroll 1
    for (int r = 1; r < 7; ++r) {
#pragma unroll
        for (int i = 0; i < 16; ++i) STEP(60, r * 16 + i, i);
    }

    // tail: bodies 112..127, no more loads; required wait 60-2k,
    // vmcnt(30) uniformly safe (stricter).
#pragma unroll
    for (int k = 0; k < 16; ++k) STEPT(30, 112 + k, k);
}

extern "C" void kernel_launch(void* const* d_in, const int* in_sizes, int n_in,
                              void* d_out, int out_size, void* d_ws, size_t ws_size,
                              hipStream_t stream) {
    const float* x        = (const float*)d_in[0];
    const float* beta_raw = (const float*)d_in[1];
    const float* p_raw    = (const float*)d_in[2];
    const float* b_raw    = (const float*)d_in[3];
    float* out            = (float*)d_out;

    dim3 grid(BN / 64);   // 512 workgroups of 1 wave
    dim3 block(64);
    snn_blocks_kernel<<<grid, block, 0, stream>>>(x, beta_raw, p_raw, b_raw, out);
}

// Round 7
// 244.194 us; speedup vs baseline: 1.2207x; 1.0274x over previous
//
#include <hip/hip_runtime.h>

// Blocks SNN forward: T=1024, TB=8, B=32, N=1024.
// One thread per (b,n) chain; 128 sequential time-blocks per thread.
// State in f64 to match the harness's float64 numpy reference on every
// heaviside decision (fp32 reassociation flips ~1e-7 margins).
//
// R7: fully compiler-visible software pipeline. R2/R3/R5/R6 all landed at
// ~87-100us = exposed load latency per body; every manual-vmcnt / opaque-asm
// scheme was nullified (R6: VGPR=132 proves the 128-VGPR frame file was
// demoted -> copies out of pending load dests force early waits). Now:
// plain C++ dwordx4 loads into a PF=8 rotating register frame file, plain
// nontemporal dwordx4 stores, LDS lane-transpose, and
// __builtin_amdgcn_sched_barrier(0) between bodies to pin program order.
// The compiler's waitcnt pass emits precise vmcnt(~28) before each frame's
// first use (m97-verified behavior). No inline-asm memory ops anywhere.

constexpr int T_LEN = 1024;
constexpr int TB    = 8;
constexpr int NBLK  = T_LEN / TB;   // 128
constexpr int BATCH = 32;
constexpr int NOUT  = 1024;
constexpr int BN    = BATCH * NOUT; // 32768 chains
constexpr int PF    = 8;            // prefetch depth (blocks) = frame count

typedef float f4 __attribute__((ext_vector_type(4)));

__global__ __launch_bounds__(64, 1)
void snn_blocks_kernel(const float* __restrict__ x,
                       const float* __restrict__ beta_raw,
                       const float* __restrict__ p_raw,
                       const float* __restrict__ b_raw,
                       float* __restrict__ out)
{
    __shared__ float inbuf[TB][64];   // 2KB: load-transpose staging
    __shared__ float sbuf[TB][64];    // 2KB: store-transpose staging

    const int lane = threadIdx.x;
    const int wg0  = blockIdx.x * 64;       // flat chain offset of this WG
    const int gid  = wg0 + lane;            // = b*NOUT + n
    const int n    = gid & (NOUT - 1);

    // 16B-per-lane split: lane i handles row (i>>4) [+4 for 2nd op],
    // cols (i&15)*4..+3 of the 64-chain stripe.
    const int rowoff = lane >> 4;
    const int coloff = wg0 + (lane & 15) * 4;

    // clamped properties (f64)
    double beta = (double)beta_raw[n];
    beta = beta < 0.001 ? 0.001 : (beta > 0.999 ? 0.999 : beta);
    double p = fabs((double)p_raw[n]);
    p = p > 0.999 ? 0.999 : p;
    double bb = fabs((double)b_raw[n]);
    bb = bb < 0.001 ? 0.001 : (bb > 1.0 ? 1.0 : bb);
    const double inv_p = 1.0 / p;

    double ppow[9];                 // p^0 .. p^8
    ppow[0] = 1.0;
#pragma unroll
    for (int i = 1; i <= 8; ++i) ppow[i] = ppow[i - 1] * p;

    double bbp[8];                  // bb * p^(t+1)
#pragma unroll
    for (int t = 0; t < 8; ++t) bbp[t] = bb * ppow[t + 1];

    // carry state
    double m = 0.0;                 // running membrane / int_mem
    double a = 0.0;                 // a_kernel scalar (a_k[t] = p^(t+1)*a)
    int    maskf = 0;               // any spike (z==1) in prev block
    int    decay = 0;               // count(z>1) in prev block
    double ssum  = 0.0;             // sum_t p^(t+1)*spike[t] of prev block
    int    zzero = 0xFF;            // bit t set if prev z[t]==0

    // rotating register frame file (constant-indexed after unrolling)
    f4 fr[PF][2];

    const float* xbase = x + (ptrdiff_t)rowoff * BN + coloff;

    // preamble: issue loads for blocks 0..PF-1 (2 x dwordx4 per block)
#pragma unroll
    for (int k = 0; k < PF; ++k) {
        fr[k][0] = *(const f4*)(xbase + (ptrdiff_t)(k * TB) * BN);
        fr[k][1] = *(const f4*)(xbase + (ptrdiff_t)(k * TB + 4) * BN);
    }

    auto body = [&](int blk, f4 v0, f4 v1) {
        // frame -> per-chain transpose via LDS (plain ds ops; compiler
        // inserts precise lgkm waits; same-wave DS executes in order)
        *(f4*)&inbuf[rowoff][(lane & 15) * 4]     = v0;
        *(f4*)&inbuf[rowoff + 4][(lane & 15) * 4] = v1;
        float cur[8];
#pragma unroll
        for (int t = 0; t < 8; ++t) cur[t] = inbuf[t][lane];

        // block header from previous block's stats
        const double a_at = a * ssum + inv_p;
        double pd = 1.0;                        // p^decay, decay in [0,8]
        pd *= (decay & 1) ? p       : 1.0;
        pd *= (decay & 2) ? ppow[2] : 1.0;
        pd *= (decay & 4) ? ppow[4] : 1.0;
        pd *= (decay & 8) ? ppow[8] : 1.0;
        const double new_a = a_at * pd;

        if (maskf) { a = new_a;     m = 0.0; }  // v_init = 0
        else       { a = ppow[8] * a;        }  // keep int_mem

        int nmaskf = 0, ndecay = 0, nzzero = 0;
        double nssum = 0.0;
        int c = 0, zc = 0;
#pragma unroll
        for (int t = 0; t < 8; ++t) {
            double xv = (double)cur[t];
            if (maskf && ((zzero >> t) & 1)) xv = 0.0;  // refractory mask
            m = beta * m + xv;                           // causal decayed sum
            const double vth = 1.0 + bbp[t] * a;         // 1 + bb*p^(t+1)*a
            const int f = (m - vth > 0.0) ? 1 : 0;       // heaviside (strict >)
            c  += f;                                     // cumsum(faulty)
            zc += c;                                     // double cumsum
            nmaskf |= (zc == 1);
            ndecay += (zc > 1) ? 1 : 0;
            nssum  += (zc == 1) ? ppow[t + 1] : 0.0;
            nzzero |= (zc == 0) ? (1 << t) : 0;
            sbuf[t][lane] = (zc == 1) ? 1.0f : 0.0f;     // stage spike
        }
        maskf = nmaskf; decay = ndecay; ssum = nssum; zzero = nzzero;

        // drain staged spikes: 2 x dwordx4 nt stores (lane-transposed)
        const float* sflat = &sbuf[0][0];
        f4 s0 = *(const f4*)(sflat + lane * 4);
        f4 s1 = *(const f4*)(sflat + 256 + lane * 4);
        __builtin_nontemporal_store(
            s0, (f4*)(out + (ptrdiff_t)(blk * TB + rowoff) * BN + coloff));
        __builtin_nontemporal_store(
            s1, (f4*)(out + (ptrdiff_t)(blk * TB + 4 + rowoff) * BN + coloff));
    };

    // steady: body blk consumes fr[blk%8] (loaded 8 bodies earlier), then
    // reloads the slot for blk+8. sched_barrier(0) pins program order so
    // loads stay 8 bodies (~28 vmcnt ops) ahead of their first use.
#pragma unroll 1
    for (int r = 0; r < NBLK / PF; ++r) {
#pragma unroll
        for (int i = 0; i < PF; ++i) {
            const int blk = r * PF + i;
            body(blk, fr[i][0], fr[i][1]);
            const int pfb = blk + PF;
            if (pfb < NBLK) {
                fr[i][0] = *(const f4*)(xbase + (ptrdiff_t)(pfb * TB) * BN);
                fr[i][1] = *(const f4*)(xbase + (ptrdiff_t)(pfb * TB + 4) * BN);
            }
            __builtin_amdgcn_sched_barrier(0);
        }
    }
}

extern "C" void kernel_launch(void* const* d_in, const int* in_sizes, int n_in,
                              void* d_out, int out_size, void* d_ws, size_t ws_size,
                              hipStream_t stream) {
    const float* x        = (const float*)d_in[0];
    const float* beta_raw = (const float*)d_in[1];
    const float* p_raw    = (const float*)d_in[2];
    const float* b_raw    = (const float*)d_in[3];
    float* out            = (float*)d_out;

    dim3 grid(BN / 64);   // 512 workgroups of 1 wave
    dim3 block(64);
    snn_blocks_kernel<<<grid, block, 0, stream>>>(x, beta_raw, p_raw, b_raw, out);
}